// Round 13
// baseline (129.879 us; speedup 1.0000x reference)
//
#include <hip/hip_runtime.h>

// DTW via min-plus scan for MI355X (gfx950). Round 13 = r12 kernel, launched
// 3x (idempotent) as a timing probe: bench = C + 3K instead of C + K.
// With r12's C + K = 80.3us, K = (bench13 - 80.3)/2. Disambiguates
// H1 (kernel ~38us, per-row VALU anomaly real) from H2 (kernel ~5-15us,
// bench pinned at a ~80us harness re-poison floor).
// Kernel body is IDENTICAL to r12 (passed, absmax 128).

#define BIGF 1e30f
#define LL   1024
#define LOUT 32

using v4f = __attribute__((ext_vector_type(4))) float;

template<int CTRL>
__device__ __forceinline__ float dpp_self(float v) {   // invalid lanes keep own
    return __int_as_float(__builtin_amdgcn_update_dpp(
        __float_as_int(v), __float_as_int(v), CTRL, 0xF, 0xF, false));
}
// validated r2-r12: whole-wave shift right 1 lane; lane 0 <- 0
__device__ __forceinline__ float wshr1z(float v) {
    return __int_as_float(__builtin_amdgcn_update_dpp(
        0, __float_as_int(v), 0x138 /*wave_shr:1*/, 0xF, 0xF, false));
}
__device__ __forceinline__ float rdlane(float v, int l) {
    return __int_as_float(__builtin_amdgcn_readlane(__float_as_int(v), l));
}

// inclusive wave64 min-scan (r9-r12-validated): 4 dpp row_shr + readlane combine
__device__ __forceinline__ float scan_min64_fast(float t, int lane) {
    t = fminf(t, dpp_self<0x111>(t));   // row_shr:1
    t = fminf(t, dpp_self<0x112>(t));   // row_shr:2
    t = fminf(t, dpp_self<0x114>(t));   // row_shr:4
    t = fminf(t, dpp_self<0x118>(t));   // row_shr:8
    float r0 = rdlane(t, 15), r1 = rdlane(t, 31), r2 = rdlane(t, 47);
    t = fminf(t, (lane >= 16) ? r0 : BIGF);
    t = fminf(t, (lane >= 32) ? r1 : BIGF);
    t = fminf(t, (lane >= 48) ? r2 : BIGF);
    return t;
}
// setup-only (r8-validated): shfl_up add scan
__device__ __forceinline__ float scan_add64(float t, int lane) {
#pragma unroll
    for (int d = 1; d < 64; d <<= 1) {
        float o = __shfl_up(t, (unsigned)d, 64);
        t += (lane >= d) ? o : 0.0f;
    }
    return t;
}

__global__ __launch_bounds__(64)
__attribute__((amdgpu_waves_per_eu(1, 1)))   // 1 wave/EU: full register file
void dtw_kernel(const float* __restrict__ x, const float* __restrict__ patts,
                float* __restrict__ out) {
    const int lane = threadIdx.x;          // lane owns cols [16*lane, 16*lane+16)
    const bool l0  = (lane == 0);
    const int blk  = blockIdx.x;           // 0..1023 = (b,n)
    const int b    = blk >> 5, n = blk & 31;
    const float* __restrict__ xb = x + b * (12 * LL);
    const float* __restrict__ pn = patts + n * (12 * 32);

    // ---- pattern params into registers: lane r (r&31) holds row r ----
    float prm[12], p2r;
    {
        const int r = lane & 31;
        float s2 = 0.f;
#pragma unroll
        for (int d = 0; d < 12; ++d) {
            float v = pn[d * 32 + r];
            s2 = fmaf(v, v, s2);
            prm[d] = -2.0f * v;
        }
        p2r = s2;
    }

    // ---- x slice -> regs (coalesced 16B/lane) ----
    float SX[12][16];
#pragma unroll
    for (int d = 0; d < 12; ++d) {
#pragma unroll
        for (int c = 0; c < 4; ++c) {
            v4f v = *(const v4f*)(xb + d * LL + 16 * lane + 4 * c);
            SX[d][4*c+0] = v.x; SX[d][4*c+1] = v.y;
            SX[d][4*c+2] = v.z; SX[d][4*c+3] = v.w;
        }
    }
    float SX2[16];
#pragma unroll
    for (int k = 0; k < 16; ++k) {
        float a = 0.f;
#pragma unroll
        for (int d = 0; d < 12; ++d) a = fmaf(SX[d][k], SX[d][k], a);
        SX2[k] = a;
    }
    // ---- inclusive prefix sums: intra-lane serial + cross-lane shfl scan ----
#pragma unroll
    for (int d = 0; d < 12; ++d) {
#pragma unroll
        for (int k = 1; k < 16; ++k) SX[d][k] += SX[d][k-1];
        float tot = SX[d][15];
        float ex  = scan_add64(tot, lane) - tot;   // exclusive lane offset
#pragma unroll
        for (int k = 0; k < 16; ++k) SX[d][k] += ex;
    }
    {
#pragma unroll
        for (int k = 1; k < 16; ++k) SX2[k] += SX2[k-1];
        float tot = SX2[15];
        float ex  = scan_add64(tot, lane) - tot;
#pragma unroll
        for (int k = 0; k < 16; ++k) SX2[k] += ex;
    }
    float jp1[16];
#pragma unroll
    for (int k = 0; k < 16; ++k) jp1[k] = (float)(16 * lane + k + 1);

    // ---- row 0: D = S(row 0) ----
    float S[16], Dp[16];
    {
        float pv[12], p2u;
#pragma unroll
        for (int d = 0; d < 12; ++d) pv[d] = rdlane(prm[d], 0);
        p2u = rdlane(p2r, 0);
#pragma unroll
        for (int k = 0; k < 16; ++k) S[k] = fmaf(p2u, jp1[k], SX2[k]);
#pragma unroll
        for (int d = 0; d < 12; ++d)
#pragma unroll
            for (int k = 0; k < 16; ++k) S[k] = fmaf(pv[d], SX[d][k], S[k]);
#pragma unroll
        for (int k = 0; k < 16; ++k) Dp[k] = S[k];
        if (lane >= 62) {
            float* ob = out + blk * (32 * LOUT) + (lane - 62) * 16;
#pragma unroll
            for (int c = 0; c < 4; ++c) {
                v4f v = {Dp[4*c], Dp[4*c+1], Dp[4*c+2], Dp[4*c+3]};
                *(v4f*)(ob + 4 * c) = v;
            }
        }
    }

    // ---- rows 1..31: zero LDS, zero barriers ----
#pragma unroll 1
    for (int i = 1; i < 32; ++i) {
        // row params via readlane (SALU broadcast, i is wave-uniform)
        float pv[12], p2u;
#pragma unroll
        for (int d = 0; d < 12; ++d) pv[d] = rdlane(prm[d], i);
        p2u = rdlane(p2r, i);

        // S(row i) for this lane's 16 columns
#pragma unroll
        for (int k = 0; k < 16; ++k) S[k] = fmaf(p2u, jp1[k], SX2[k]);
#pragma unroll
        for (int d = 0; d < 12; ++d)
#pragma unroll
            for (int k = 0; k < 16; ++k) S[k] = fmaf(pv[d], SX[d][k], S[k]);

        // boundary values from the left neighbor (validated primitive)
        float dsh = wshr1z(Dp[15]); dsh = l0 ? BIGF : dsh;  // D_prev[j-1] at k=0
        float se  = wshr1z(S[15]);                          // S[j-1] at k=0 (lane0->0)

        // z[k] = a[k] - S[k-1]; intra-lane inclusive min-scan m
        float m[16];
        m[0] = fminf(dsh, Dp[0]) - se;
#pragma unroll
        for (int k = 1; k < 16; ++k)
            m[k] = fminf(m[k-1], fminf(Dp[k-1], Dp[k]) - S[k-1]);

        // cross-lane inclusive min-scan of lane totals, then exclusive
        float t  = scan_min64_fast(m[15], lane);
        float te = wshr1z(t); te = l0 ? BIGF : te;

#pragma unroll
        for (int k = 0; k < 16; ++k) Dp[k] = S[k] + fminf(te, m[k]);

        if (lane >= 62) {
            float* ob = out + blk * (32 * LOUT) + (lane - 62) * 16;
#pragma unroll
            for (int c = 0; c < 4; ++c) {
                v4f v = {Dp[4*c], Dp[4*c+1], Dp[4*c+2], Dp[4*c+3]};
                *(v4f*)(ob + i * 32 + 4 * c) = v;
            }
        }
    }
}

extern "C" void kernel_launch(void* const* d_in, const int* in_sizes, int n_in,
                              void* d_out, int out_size, void* d_ws, size_t ws_size,
                              hipStream_t stream) {
    const float* x     = (const float*)d_in[0];   // [32,12,1024] f32
    const float* patts = (const float*)d_in[1];   // [32,12,32]   f32
    float* out         = (float*)d_out;           // [32,32,32,32] f32
    // 3 identical idempotent launches: bench = C + 3K -> K = (bench - 80.3)/2
    dtw_kernel<<<dim3(1024), dim3(64), 0, stream>>>(x, patts, out);
    dtw_kernel<<<dim3(1024), dim3(64), 0, stream>>>(x, patts, out);
    dtw_kernel<<<dim3(1024), dim3(64), 0, stream>>>(x, patts, out);
}

// Round 14
// 76.793 us; speedup vs baseline: 1.6913x; 1.6913x over previous
//
#include <hip/hip_runtime.h>

// DTW via min-plus scan for MI355X (gfx950). Round 14.
// B=32, N=32, D=12, P=32, L=1024, L_OUT=32, RHO=1 => w=1.
// Row recurrence as prefix scan:  S[j] = prefix_sum(cost[i,:]),
//   D[j] = S[j] + prefix_min_k(a[k]-S[k-1]),  a[k]=min(Dprev[k-1],Dprev[k]).
// Lanes = columns (16 cols/lane, one wave per (b,n) problem). Rows serial.
// r13 probe: kernel K ~= 25us, harness floor C ~= 55us.
// r14 vs r12: (1) S/SX/SX2 as float2 -> v_pk_fma_f32 halves the dominant
// 208-fma/row S-compute; (2) setup prefix-add scans via dpp row_shr
// (zero-fill) + readlane combine instead of 13x6 dependent ds_bpermute;
// (3) unroll 2 so row i+1's independent S fmas fill row i's scan chain.

#define BIGF 1e30f
#define LL   1024
#define LOUT 32

using v4f = __attribute__((ext_vector_type(4))) float;
using v2f = __attribute__((ext_vector_type(2))) float;

__device__ __forceinline__ v2f fma2(v2f a, v2f b, v2f c) {
    return __builtin_elementwise_fma(a, b, c);
}
__device__ __forceinline__ v2f bc2(float s) { v2f r = {s, s}; return r; }

template<int CTRL>
__device__ __forceinline__ float dpp_self(float v) {   // invalid lanes keep own
    return __int_as_float(__builtin_amdgcn_update_dpp(
        __float_as_int(v), __float_as_int(v), CTRL, 0xF, 0xF, false));
}
template<int CTRL>
__device__ __forceinline__ float dpp_zero(float v) {   // invalid lanes get 0
    return __int_as_float(__builtin_amdgcn_update_dpp(
        0, __float_as_int(v), CTRL, 0xF, 0xF, false));
}
// validated r2-r13: whole-wave shift right 1 lane; lane 0 <- 0
__device__ __forceinline__ float wshr1z(float v) {
    return __int_as_float(__builtin_amdgcn_update_dpp(
        0, __float_as_int(v), 0x138 /*wave_shr:1*/, 0xF, 0xF, false));
}
__device__ __forceinline__ float rdlane(float v, int l) {
    return __int_as_float(__builtin_amdgcn_readlane(__float_as_int(v), l));
}

// inclusive wave64 min-scan (r9-r13-validated): 4 dpp row_shr + readlane combine
__device__ __forceinline__ float scan_min64_fast(float t, int lane) {
    t = fminf(t, dpp_self<0x111>(t));   // row_shr:1
    t = fminf(t, dpp_self<0x112>(t));   // row_shr:2
    t = fminf(t, dpp_self<0x114>(t));   // row_shr:4
    t = fminf(t, dpp_self<0x118>(t));   // row_shr:8
    float r0 = rdlane(t, 15), r1 = rdlane(t, 31), r2 = rdlane(t, 47);
    t = fminf(t, (lane >= 16) ? r0 : BIGF);
    t = fminf(t, (lane >= 32) ? r1 : BIGF);
    t = fminf(t, (lane >= 48) ? r2 : BIGF);
    return t;
}
// inclusive wave64 add-scan: same structure, zero-fill hops (no bpermute).
// row_shr zero-fill validated (wshr1z family); per-16-row Hillis-Steele.
__device__ __forceinline__ float scan_add64_dpp(float t, int lane) {
    t += dpp_zero<0x111>(t);
    t += dpp_zero<0x112>(t);
    t += dpp_zero<0x114>(t);
    t += dpp_zero<0x118>(t);
    float r0 = rdlane(t, 15), r1 = rdlane(t, 31), r2 = rdlane(t, 47);
    t += (lane >= 16) ? r0 : 0.0f;
    t += (lane >= 32) ? r1 : 0.0f;
    t += (lane >= 48) ? r2 : 0.0f;
    return t;
}

__global__ __launch_bounds__(64)
__attribute__((amdgpu_waves_per_eu(1, 1)))   // 1 wave/EU: full register file
void dtw_kernel(const float* __restrict__ x, const float* __restrict__ patts,
                float* __restrict__ out) {
    const int lane = threadIdx.x;          // lane owns cols [16*lane, 16*lane+16)
    const bool l0  = (lane == 0);
    const int blk  = blockIdx.x;           // 0..1023 = (b,n)
    const int b    = blk >> 5, n = blk & 31;
    const float* __restrict__ xb = x + b * (12 * LL);
    const float* __restrict__ pn = patts + n * (12 * 32);

    // ---- pattern params into registers: lane r (r&31) holds row r ----
    float prm[12], p2r;
    {
        const int r = lane & 31;
        float s2 = 0.f;
#pragma unroll
        for (int d = 0; d < 12; ++d) {
            float v = pn[d * 32 + r];
            s2 = fmaf(v, v, s2);
            prm[d] = -2.0f * v;
        }
        p2r = s2;
    }

    // ---- x slice -> packed regs (coalesced 16B/lane) ----
    v2f SXp[12][8];
#pragma unroll
    for (int d = 0; d < 12; ++d) {
#pragma unroll
        for (int c = 0; c < 4; ++c) {
            v4f v = *(const v4f*)(xb + d * LL + 16 * lane + 4 * c);
            v2f lo = {v.x, v.y}, hi = {v.z, v.w};
            SXp[d][2 * c]     = lo;
            SXp[d][2 * c + 1] = hi;
        }
    }
    // x^2 (packed, from raw values)
    v2f SX2p[8];
#pragma unroll
    for (int j = 0; j < 8; ++j) {
        v2f t = SXp[0][j] * SXp[0][j];
#pragma unroll
        for (int d = 1; d < 12; ++d) t = fma2(SXp[d][j], SXp[d][j], t);
        SX2p[j] = t;
    }
    // ---- inclusive prefix sums: intra-lane serial + dpp add-scan ----
#pragma unroll
    for (int d = 0; d < 12; ++d) {
        float run = 0.f;
#pragma unroll
        for (int j = 0; j < 8; ++j) {
            float a0 = SXp[d][j].x + run;
            float a1 = SXp[d][j].y + a0;
            SXp[d][j].x = a0; SXp[d][j].y = a1; run = a1;
        }
        float ex = scan_add64_dpp(run, lane) - run;   // exclusive lane offset
        v2f exv = bc2(ex);
#pragma unroll
        for (int j = 0; j < 8; ++j) SXp[d][j] += exv;
    }
    {
        float run = 0.f;
#pragma unroll
        for (int j = 0; j < 8; ++j) {
            float a0 = SX2p[j].x + run;
            float a1 = SX2p[j].y + a0;
            SX2p[j].x = a0; SX2p[j].y = a1; run = a1;
        }
        float ex = scan_add64_dpp(run, lane) - run;
        v2f exv = bc2(ex);
#pragma unroll
        for (int j = 0; j < 8; ++j) SX2p[j] += exv;
    }
    v2f jp1p[8];
#pragma unroll
    for (int j = 0; j < 8; ++j) {
        v2f t = {(float)(16 * lane + 2 * j + 1), (float)(16 * lane + 2 * j + 2)};
        jp1p[j] = t;
    }

    // ---- row 0: D = S(row 0) ----
    v2f S2[8];
    float Dp[16];
    {
        float pv[12], p2u;
#pragma unroll
        for (int d = 0; d < 12; ++d) pv[d] = rdlane(prm[d], 0);
        p2u = rdlane(p2r, 0);
#pragma unroll
        for (int j = 0; j < 8; ++j) S2[j] = fma2(bc2(p2u), jp1p[j], SX2p[j]);
#pragma unroll
        for (int d = 0; d < 12; ++d)
#pragma unroll
            for (int j = 0; j < 8; ++j) S2[j] = fma2(bc2(pv[d]), SXp[d][j], S2[j]);
#pragma unroll
        for (int k = 0; k < 16; ++k) Dp[k] = S2[k >> 1][k & 1];
        if (lane >= 62) {
            float* ob = out + blk * (32 * LOUT) + (lane - 62) * 16;
#pragma unroll
            for (int c = 0; c < 4; ++c) {
                v4f v = {Dp[4*c], Dp[4*c+1], Dp[4*c+2], Dp[4*c+3]};
                *(v4f*)(ob + 4 * c) = v;
            }
        }
    }

    // ---- rows 1..31: zero LDS, zero barriers; unroll 2 for cross-row ILP ----
#pragma unroll 2
    for (int i = 1; i < 32; ++i) {
        // row params via readlane (uniform index)
        float pv[12], p2u;
#pragma unroll
        for (int d = 0; d < 12; ++d) pv[d] = rdlane(prm[d], i);
        p2u = rdlane(p2r, i);

        // S(row i), packed: 104 v_pk_fma_f32
#pragma unroll
        for (int j = 0; j < 8; ++j) S2[j] = fma2(bc2(p2u), jp1p[j], SX2p[j]);
#pragma unroll
        for (int d = 0; d < 12; ++d)
#pragma unroll
            for (int j = 0; j < 8; ++j) S2[j] = fma2(bc2(pv[d]), SXp[d][j], S2[j]);

        // boundary values from the left neighbor
        float dsh = wshr1z(Dp[15]); dsh = l0 ? BIGF : dsh;  // D_prev[j-1] at k=0
        float se  = wshr1z(S2[7].y);                        // S[j-1] at k=0 (lane0->0)

        // z[k] = a[k] - S[k-1]; intra-lane inclusive min-scan m
        float m[16];
        m[0] = fminf(dsh, Dp[0]) - se;
#pragma unroll
        for (int k = 1; k < 16; ++k)
            m[k] = fminf(m[k-1],
                         fminf(Dp[k-1], Dp[k]) - S2[(k-1) >> 1][(k-1) & 1]);

        // cross-lane inclusive min-scan of lane totals, then exclusive
        float t  = scan_min64_fast(m[15], lane);
        float te = wshr1z(t); te = l0 ? BIGF : te;

#pragma unroll
        for (int k = 0; k < 16; ++k)
            Dp[k] = S2[k >> 1][k & 1] + fminf(te, m[k]);

        if (lane >= 62) {
            float* ob = out + blk * (32 * LOUT) + (lane - 62) * 16;
#pragma unroll
            for (int c = 0; c < 4; ++c) {
                v4f v = {Dp[4*c], Dp[4*c+1], Dp[4*c+2], Dp[4*c+3]};
                *(v4f*)(ob + i * 32 + 4 * c) = v;
            }
        }
    }
}

extern "C" void kernel_launch(void* const* d_in, const int* in_sizes, int n_in,
                              void* d_out, int out_size, void* d_ws, size_t ws_size,
                              hipStream_t stream) {
    const float* x     = (const float*)d_in[0];   // [32,12,1024] f32
    const float* patts = (const float*)d_in[1];   // [32,12,32]   f32
    float* out         = (float*)d_out;           // [32,32,32,32] f32
    dtw_kernel<<<dim3(1024), dim3(64), 0, stream>>>(x, patts, out);
}